// Round 9
// baseline (32.654 us; speedup 1.0000x reference)
//
#include <hip/hip_runtime.h>
#include <math.h>

#define THREADS 1024  // 1024-thread blocks: 2 blocks/CU, fewest partials for finalize
#define PPT 4         // pixels per thread; block covers 4096 contiguous pixels

__device__ __forceinline__ float frcp(float x)  { return __builtin_amdgcn_rcpf(x); }
__device__ __forceinline__ float fsqrt(float x) { return __builtin_amdgcn_sqrtf(x); }

__device__ __forceinline__ float fast_sigmoid(float x) {
    return frcp(1.0f + __expf(-x));
}

// skimage-style rgb2hsv, H and V only
__device__ __forceinline__ void rgb2hv(float r, float g, float b,
                                       float& h, float& v) {
    float maxc = fmaxf(r, fmaxf(g, b));
    float minc = fminf(r, fminf(g, b));
    float delta = maxc - minc;
    float rd = frcp((delta == 0.0f) ? 1.0f : delta);
    float hh;
    if (maxc == r)      hh = (g - b) * rd;
    else if (maxc == g) hh = 2.0f + (b - r) * rd;
    else                hh = 4.0f + (r - g) * rd;
    hh = hh * (1.0f / 6.0f);
    hh = hh - floorf(hh);          // (h/6) mod 1.0
    h = (delta == 0.0f) ? 0.0f : hh;
    v = maxc;
}

__device__ __forceinline__ float pixel_loss(
    float gr, float gg, float gb,
    float br, float bgc, float bb,
    float fr, float fgc, float fb,
    float u, float threshold, int it)
{
    if (it > 300) {
        float hg, vg, hb, vb;
        rgb2hv(gr, gg, gb, hg, vg);
        rgb2hv(br, bgc, bb, hb, vb);
        float dh = hg - hb;
        float dv = vg - vb;
        float diff = fsqrt(dh * dh + dv * dv);
        float mask = fast_sigmoid((diff - threshold) * 10.0f);

        float d0 = gr - br, d1 = gg - bgc, d2 = gb - bb;
        float bg_mse = (d0 * d0 + d1 * d1 + d2 * d2) * (1.0f / 3.0f);

        float e0 = gr - fr, e1 = gg - fgc, e2 = gb - fb;
        float fg_mse = (e0 * e0 + e1 * e1 + e2 * e2) * (1.0f / 3.0f);
        float fg_perray = fg_mse * 0.5f * frcp(u * u) + __logf(u);

        return bg_mse + (fg_perray - bg_mse) * mask;
    } else {
        float d0 = gr - br, d1 = gg - bgc, d2 = gb - bb;
        return d0 * d0 + d1 * d1 + d2 * d2;  // denom = 3N in this branch
    }
}

__global__ __launch_bounds__(THREADS) void loss_kernel(
    const float* __restrict__ gt, const float* __restrict__ bg,
    const float* __restrict__ fg, const float* __restrict__ unc,
    const float* __restrict__ thr_param, const int* __restrict__ iter_p,
    double* __restrict__ partials, int n_pix)
{
    const int t = blockIdx.x * blockDim.x + threadIdx.x;
    const int p0 = t * PPT;
    const int it = iter_p[0];
    const float threshold = 1.414f * (1.0f - fast_sigmoid(thr_param[0]));

    float local = 0.0f;

    if (p0 + PPT <= n_pix) {
        const float4* g4 = (const float4*)gt + 3 * t;
        const float4* b4 = (const float4*)bg + 3 * t;
        const float4* f4 = (const float4*)fg + 3 * t;
        float4 ga = g4[0], gbv = g4[1], gc = g4[2];
        float4 ba = b4[0], bbv = b4[1], bc = b4[2];
        float4 fa = f4[0], fbv = f4[1], fc = f4[2];
        float4 u4 = *(const float4*)(unc + p0);

        float G[12] = {ga.x, ga.y, ga.z, ga.w, gbv.x, gbv.y, gbv.z, gbv.w,
                       gc.x, gc.y, gc.z, gc.w};
        float B[12] = {ba.x, ba.y, ba.z, ba.w, bbv.x, bbv.y, bbv.z, bbv.w,
                       bc.x, bc.y, bc.z, bc.w};
        float F[12] = {fa.x, fa.y, fa.z, fa.w, fbv.x, fbv.y, fbv.z, fbv.w,
                       fc.x, fc.y, fc.z, fc.w};
        float U[4] = {u4.x, u4.y, u4.z, u4.w};

        #pragma unroll
        for (int j = 0; j < PPT; ++j) {
            local += pixel_loss(G[3*j], G[3*j+1], G[3*j+2],
                                B[3*j], B[3*j+1], B[3*j+2],
                                F[3*j], F[3*j+1], F[3*j+2],
                                U[j], threshold, it);
        }
    } else if (p0 < n_pix) {
        for (int p = p0; p < n_pix; ++p) {
            local += pixel_loss(gt[3*p], gt[3*p+1], gt[3*p+2],
                                bg[3*p], bg[3*p+1], bg[3*p+2],
                                fg[3*p], fg[3*p+1], fg[3*p+2],
                                unc[p], threshold, it);
        }
    }

    // 64-lane wave reduce
    #pragma unroll
    for (int off = 32; off > 0; off >>= 1)
        local += __shfl_down(local, off, 64);

    __shared__ double wsum[THREADS / 64];
    const int lane = threadIdx.x & 63;
    const int wid = threadIdx.x >> 6;
    if (lane == 0) wsum[wid] = (double)local;
    __syncthreads();
    if (threadIdx.x == 0) {
        double s = 0.0;
        #pragma unroll
        for (int w = 0; w < THREADS / 64; ++w) s += wsum[w];
        partials[blockIdx.x] = s;   // one slot per block, no atomics
    }
}

__global__ __launch_bounds__(1024) void finalize_kernel(
    const double* __restrict__ partials, int n_part,
    const int* __restrict__ iter_p, float* __restrict__ out, int n_pix)
{
    double s = 0.0;
    for (int i = threadIdx.x; i < n_part; i += 1024)
        s += partials[i];
    #pragma unroll
    for (int off = 32; off > 0; off >>= 1)
        s += __shfl_down(s, off, 64);

    __shared__ double wsum[16];
    const int lane = threadIdx.x & 63;
    const int wid = threadIdx.x >> 6;
    if (lane == 0) wsum[wid] = s;
    __syncthreads();
    if (threadIdx.x == 0) {
        double tot = 0.0;
        #pragma unroll
        for (int w = 0; w < 16; ++w) tot += wsum[w];
        double denom = (iter_p[0] > 300) ? (double)n_pix : 3.0 * (double)n_pix;
        out[0] = (float)(tot / denom);
    }
}

extern "C" void kernel_launch(void* const* d_in, const int* in_sizes, int n_in,
                              void* d_out, int out_size, void* d_ws, size_t ws_size,
                              hipStream_t stream) {
    const float* gt  = (const float*)d_in[0];
    const float* bg  = (const float*)d_in[1];
    const float* fg  = (const float*)d_in[2];
    // d_in[3] = FG_acc : unused by reference
    const float* unc = (const float*)d_in[4];   // FG_uncertainties [N,1]
    const float* thr = (const float*)d_in[5];   // threshold_param
    // d_in[6] = steepness : unused (0.1 hard-coded in reference)
    const int*  iter = (const int*)d_in[7];

    const int n_pix = in_sizes[0] / 3;
    const int total_threads = (n_pix + PPT - 1) / PPT;
    const int blocks = (total_threads + THREADS - 1) / THREADS;  // 1024

    double* partials = (double*)d_ws;

    loss_kernel<<<blocks, THREADS, 0, stream>>>(gt, bg, fg, unc, thr, iter,
                                                partials, n_pix);
    finalize_kernel<<<1, 1024, 0, stream>>>(partials, blocks, iter,
                                            (float*)d_out, n_pix);
}